// Round 13
// baseline (330.765 us; speedup 1.0000x reference)
//
#include <hip/hip_runtime.h>
#include <stdint.h>

// CORDIV stochastic-computing divider — Round 13: fully hand-scheduled VMEM
// (asm loads AND asm stores), zero LDS, full occupancy, rotating q-buffer.
//
// R12: 115.5us (384MB @ 3.32 TB/s eff) = 88% of the R8-measured same-mix
// streaming ceiling (102us / 3.76 TB/s). Residual suspects: (a) LDS
// round-trip, (b) compiler store-hazard waits: before reusing a store's
// source VGPRs the compiler emits vmcnt(N) counting only ITS ops — with our
// invisible prefetch loads in the same FIFO, that drains the pipeline.
//
// This round removes both: every VMEM op is asm (compiler emits ZERO
// waitcnt); store-source safety is proven by construction:
//  - qbuf[4] rotates: q(t) -> qbuf[t&3]; sr[i] at step t == qbuf[(t-1-i)&3]
//    (the shift register IS the rotation — no copies, no aliasing).
//  - slot t&3 is redefined at step t; its pending store is store(t-4),
//    which is OLDER than loads(t) (iter t-4 vs t-3), so wait(t) -> retired.
//  - depth-3 load pipeline; steady wait vmcnt(6) = 2 stores + 4 loads
//    younger; vmcnt never reaches 0 mid-loop.
// Init: qbuf = {s3,s2,s1,s0} so qbuf[(-1-i)&3] = sr_init[i].
// VGPR ~48 -> 8 waves/SIMD; grid 2048 = 8 blocks/CU, exact coverage.

#define SC_T 16

typedef float v4f __attribute__((ext_vector_type(4)));

__device__ __forceinline__ v4f gload(const v4f* __restrict__ p) {
    v4f r;
    asm volatile("global_load_dwordx4 %0, %1, off" : "=v"(r) : "v"(p));
    return r;
}

__device__ __forceinline__ void gstore(v4f v, v4f* __restrict__ p) {
    asm volatile("global_store_dwordx4 %0, %1, off" :: "v"(p), "v"(v) : "memory");
}

// Ops younger than plane-t's 2 loads at its wait point.
// Order: ISSUE(0),ISSUE(1),ISSUE(2); iter k: [wait, compute, store(k), ISSUE(k+3)].
//   t==0 : loads(1),loads(2)                          -> 4
//   t==1 : loads(2),store(0),loads(3)                 -> 5
//   2..13: store(t-2),loads(t+1),store(t-1),loads(t+2)-> 6
//   t==14: store(12),loads(15),store(13)              -> 4
//   t==15: store(13),store(14)                        -> 2
#define WAITN(t) (1 * ((t) >= 1) + 1 * ((t) >= 2) + \
                  2 * ((t) + 1 < SC_T) + 2 * ((t) + 2 < SC_T))

__global__ __launch_bounds__(256) void cordiv_kernel(
    const v4f*   __restrict__ dividend,
    const v4f*   __restrict__ divisor,
    const float* __restrict__ sr_init_f,   // [BUF_DEP, N] — lane-uniform rows
    const int*   __restrict__ rng_table,
    v4f*         __restrict__ out,
    int n4)   // N / 4 = 524288
{
    const int gid = blockIdx.x * 256 + threadIdx.x;   // grid covers n4 exactly

    const size_t nElem = (size_t)n4 * 4;    // N

    // rng table (uniform) + sr rows (lane-uniform by semantic contract).
    int   r0 = rng_table[0];
    int   r1 = rng_table[1];
    int   r2 = rng_table[2];
    int   r3 = rng_table[3];
    float s0 = sr_init_f[0 * nElem];
    float s1 = sr_init_f[1 * nElem];
    float s2 = sr_init_f[2 * nElem];
    float s3 = sr_init_f[3 * nElem];
    // Pin: the compiler's waitcnt for these loads lands HERE, before any of
    // our invisible asm loads enter the VMEM FIFO.
    asm volatile("" : "+v"(r0), "+v"(r1), "+v"(r2), "+v"(r3),
                      "+v"(s0), "+v"(s1), "+v"(s2), "+v"(s3));
    const int rtab[4] = {r0, r1, r2, r3};

    // Rotating quotient buffer == shift register (see header comment).
    v4f qbuf[4];
    qbuf[0] = (v4f){s3, s3, s3, s3};
    qbuf[1] = (v4f){s2, s2, s2, s2};
    qbuf[2] = (v4f){s1, s1, s1, s1};
    qbuf[3] = (v4f){s0, s0, s0, s0};

    // 3-deep rotating load buffers.
    v4f bD[3], bS[3];

#define ISSUE(t) do {                                                     \
        bD[(t) % 3] = gload(dividend + (size_t)(t) * n4 + gid);           \
        bS[(t) % 3] = gload(divisor  + (size_t)(t) * n4 + gid);           \
    } while (0)

#define STEP(t) do {                                                      \
        asm volatile("s_waitcnt vmcnt(%c2)"                               \
                     : "+v"(bD[(t) % 3]), "+v"(bS[(t) % 3])               \
                     : "i"(WAITN(t)) : "memory");                         \
        const int r_ = rtab[(t) & 3];                                     \
        /* sr[i] == qbuf[(t-1-i)&3]; slot indices are compile-time */     \
        const v4f hq = (r_ == 0) ? qbuf[((t) + 3) & 3]                    \
                     : (r_ == 1) ? qbuf[((t) + 2) & 3]                    \
                     : (r_ == 2) ? qbuf[((t) + 1) & 3]                    \
                     :             qbuf[(t) & 3];                         \
        const v4f dvd = bD[(t) % 3];                                      \
        const v4f dvs = bS[(t) % 3];                                      \
        v4f q;                                                            \
        q.x = (dvs.x == 1.0f) ? dvd.x : hq.x;                             \
        q.y = (dvs.y == 1.0f) ? dvd.y : hq.y;                             \
        q.z = (dvs.z == 1.0f) ? dvd.z : hq.z;                             \
        q.w = (dvs.w == 1.0f) ? dvd.w : hq.w;                             \
        qbuf[(t) & 3] = q;    /* store(t-4) retired by wait(t) -> safe */ \
        gstore(q, out + (size_t)(t) * n4 + gid);                          \
        if ((t) + 3 < SC_T) ISSUE((t) + 3);                               \
    } while (0)

    // Prologue: three planes in flight.
    ISSUE(0);
    ISSUE(1);
    ISSUE(2);

    STEP(0);  STEP(1);  STEP(2);  STEP(3);
    STEP(4);  STEP(5);  STEP(6);  STEP(7);
    STEP(8);  STEP(9);  STEP(10); STEP(11);
    STEP(12); STEP(13); STEP(14); STEP(15);

#undef STEP
#undef ISSUE
}

extern "C" void kernel_launch(void* const* d_in, const int* in_sizes, int n_in,
                              void* d_out, int out_size, void* d_ws, size_t ws_size,
                              hipStream_t stream) {
    const float* dividend = (const float*)d_in[0];   // [T, N]
    const float* divisor  = (const float*)d_in[1];   // [T, N]
    const float* sr_init  = (const float*)d_in[2];   // [BUF_DEP, N]
    const int*   rng      = (const int*)d_in[3];     // [4]
    float*       out      = (float*)d_out;           // [T, N]

    const int n  = in_sizes[0] / SC_T;   // N = 2^21
    const int n4 = n / 4;                // 524288

    const int grid = n4 / 256;           // 2048 blocks = 8/CU, exact coverage

    cordiv_kernel<<<grid, 256, 0, stream>>>(
        (const v4f*)dividend, (const v4f*)divisor,
        sr_init, rng, (v4f*)out, n4);
}